// Round 15
// baseline (1596.511 us; speedup 1.0000x reference)
//
#include <hip/hip_runtime.h>
#include <hip/hip_fp16.h>

// DIAGNOSTIC ROUND: real R12 kernel (correct output) + 4 probe kernels that
// write junk into a masked ws window. Probes have internal repeats (x3/x8) so
// their per-dispatch dur_us exceeds the harness fillBuffer rows (~340us) and
// lands in the rocprof top-5. Headline dur_us is intentionally inflated this
// round; it buys attribution of the 290-300us plateau:
//   kA x3: full loop, stores -> ws (L2-resident)  => HBM-store backpressure
//   kB x3: LDS reads replaced by register junk    => LDS path total
//   kD x3: LDS reads issued, values asm-sunk      => LDS pipe vs latency
//   kC x8: stage+convert+barrier only             => per-block overhead floor

#define B_      2
#define C_      256
#define N_      512
#define NENT    (N_ * 7)
#define SP      66
#define THREADS 512
#define GROUPS  10
#define REC_F_BASE 128
#define WS_NEEDED ((size_t)REC_F_BASE * 4 + (size_t)B_ * NENT * 8 * 4)  // 229888 B

typedef _Float16 h2v __attribute__((ext_vector_type(2)));

__device__ __forceinline__ float gcoord(float lo, float hi, int i) {
    return lo + (hi - lo) * (1.0f / 6.0f) * (float)i;
}
__device__ __forceinline__ uint32_t pkrtz(float a, float b) {
    auto h = __builtin_amdgcn_cvt_pkrtz(a, b);
    return __builtin_bit_cast(uint32_t, h);
}
__device__ __forceinline__ float xlerp(uint32_t pkv, uint32_t pkw) {
#if __has_builtin(__builtin_amdgcn_fdot2)
    return __builtin_amdgcn_fdot2(__builtin_bit_cast(h2v, pkv),
                                  __builtin_bit_cast(h2v, pkw), 0.0f, false);
#else
    h2v v = __builtin_bit_cast(h2v, pkv);
    h2v w = __builtin_bit_cast(h2v, pkw);
    return (float)v[0] * (float)w[0] + (float)v[1] * (float)w[1];
#endif
}

// ---- kernel 1: bucket + per-entry record ----
__global__ __launch_bounds__(256) void bucket_kernel(
    const float* __restrict__ props, int* __restrict__ wsi, float* __restrict__ wsf)
{
    int b = blockIdx.x;
    __shared__ int counts[63];
    __shared__ int starts[64];
    __shared__ int cursors[63];
    int tid = threadIdx.x;
    if (tid < 63) counts[tid] = 0;
    __syncthreads();
    for (int e = tid; e < NENT; e += 256) {
        int n = e / 7, iz = e - n * 7;
        const float* pr = props + (size_t)(b * N_ + n) * 6;
        float gz = gcoord(pr[2], pr[5], iz);
        int z0 = min(max((int)gz, 0), 62);
        atomicAdd(&counts[z0], 1);
    }
    __syncthreads();
    if (tid == 0) {
        int s = 0;
        for (int k = 0; k < 63; ++k) { starts[k] = s; s += counts[k]; }
        starts[63] = s;
    }
    __syncthreads();
    if (tid < 63) cursors[tid] = starts[tid];
    __syncthreads();
    for (int e = tid; e < NENT; e += 256) {
        int n = e / 7, iz = e - n * 7;
        const float* pr = props + (size_t)(b * N_ + n) * 6;
        float x1p = pr[0], y1p = pr[1], z1p = pr[2];
        float x2p = pr[3], y2p = pr[4], z2p = pr[5];
        float gz = gcoord(z1p, z2p, iz);
        int z0 = min(max((int)gz, 0), 62);
        float wz = gz - (float)z0;
        int pos = atomicAdd(&cursors[z0], 1);
        int off = (b * N_ + n) * (C_ * 343) + iz * 49;
        float* r = wsf + REC_F_BASE + (size_t)(b * NENT + pos) * 8;
        r[0] = x1p; r[1] = (x2p - x1p) * (1.0f / 6.0f);
        r[2] = y1p; r[3] = (y2p - y1p) * (1.0f / 6.0f);
        r[4] = wz;  r[5] = __int_as_float(off);
        r[6] = 0.0f; r[7] = 0.0f;
    }
    if (tid < 64) wsi[b * 64 + tid] = starts[tid];
}

// common prologue macro: decode block, CSR bounds, stage+convert, lane map
#define PROLOGUE()                                                          \
    __shared__ __align__(16) uint2 pk2[64 * SP];                            \
    int bid = blockIdx.x;                                                   \
    int s   = bid & 511;                                                    \
    int z0  = bid >> 9;                                                     \
    int b   = s >> 8;                                                       \
    int c   = s & 255; (void)c;                                             \
    int tid = threadIdx.x;                                                  \
    int base = wsi[b * 64 + z0];                                            \
    int end  = wsi[b * 64 + z0 + 1];                                        \
    if (base == end) return;                                                \
    const float* vol = feat + ((size_t)s << 18) + ((size_t)z0 << 12);       \
    int y  = tid >> 3;                                                      \
    int x8 = (tid & 7) << 3;                                                \
    const float* src = vol + y * 64 + x8;                                   \
    float4 p0a = *(const float4*)(src);                                     \
    float4 p0b = *(const float4*)(src + 4);                                 \
    float4 p1a = *(const float4*)(src + 4096);                              \
    float4 p1b = *(const float4*)(src + 4100);                              \
    int g = tid / 49;                                                       \
    int p = tid - g * 49;                                                   \
    int iy = p / 7;                                                         \
    float fx = (float)(p - iy * 7);                                         \
    float fy = (float)iy;                                                   \
    const float4* recs2 = (const float4*)(wsf + REC_F_BASE)                 \
                          + (size_t)(b * NENT) * 2;                         \
    int myEnd = (g < GROUPS) ? end : base;                                  \
    int e0 = base + g;

#define CONVERT_WRITE()                                                     \
    {                                                                       \
        float n0 = __shfl_down(p0a.x, 1);                                   \
        float n1 = __shfl_down(p1a.x, 1);                                   \
        uint4* d = (uint4*)&pk2[y * SP + x8];                               \
        uint4 w0, w1, w2, w3;                                               \
        w0.x = pkrtz(p0a.x, p0a.y); w0.y = pkrtz(p1a.x, p1a.y);             \
        w0.z = pkrtz(p0a.y, p0a.z); w0.w = pkrtz(p1a.y, p1a.z);             \
        w1.x = pkrtz(p0a.z, p0a.w); w1.y = pkrtz(p1a.z, p1a.w);             \
        w1.z = pkrtz(p0a.w, p0b.x); w1.w = pkrtz(p1a.w, p1b.x);             \
        w2.x = pkrtz(p0b.x, p0b.y); w2.y = pkrtz(p1b.x, p1b.y);             \
        w2.z = pkrtz(p0b.y, p0b.z); w2.w = pkrtz(p1b.y, p1b.z);             \
        w3.x = pkrtz(p0b.z, p0b.w); w3.y = pkrtz(p1b.z, p1b.w);             \
        w3.z = pkrtz(p0b.w, n0);    w3.w = pkrtz(p1b.w, n1);                \
        d[0] = w0; d[1] = w1; d[2] = w2; d[3] = w3;                         \
    }

// ---- REAL kernel (R12, correct) ----
__global__ __launch_bounds__(THREADS, 8) void roialign3d_small_kernel(
    const float* __restrict__ feat, const int* __restrict__ wsi,
    const float* __restrict__ wsf, float* __restrict__ out)
{
    PROLOGUE();
    int e = e0;
    float4 rA, rB, rAn, rBn;
    if (e < myEnd) {
        rA = recs2[(size_t)e * 2]; rB = recs2[(size_t)e * 2 + 1];
        if (e + GROUPS < myEnd) {
            rAn = recs2[(size_t)(e + GROUPS) * 2];
            rBn = recs2[(size_t)(e + GROUPS) * 2 + 1];
        }
    }
    CONVERT_WRITE();
    __syncthreads();
    float* outc = out + (size_t)c * 343;
    while (e < myEnd) {
        float gx = fmaf(rA.y, fx, rA.x);
        float gy = fmaf(rA.w, fy, rA.z);
        int x0 = (int)gx, y0 = (int)gy;
        float wx = __builtin_amdgcn_fractf(gx);
        float wy = __builtin_amdgcn_fractf(gy);
        uint32_t pw = pkrtz(1.0f - wx, wx);
        float wz = rB.x;
        int offc = __float_as_int(rB.y);
        int sl = y0 * SP + x0;
        uint2 q0 = pk2[sl], q1 = pk2[sl + SP];
        float4 tA = rAn, tB = rBn;
        int e2 = e + 2 * GROUPS;
        if (e2 < myEnd) {
            rAn = recs2[(size_t)e2 * 2];
            rBn = recs2[(size_t)e2 * 2 + 1];
        }
        float c00 = xlerp(q0.x, pw);
        float c10 = xlerp(q0.y, pw);
        float c01 = xlerp(q1.x, pw);
        float c11 = xlerp(q1.y, pw);
        float d0 = fmaf(c01 - c00, wy, c00);
        float d1 = fmaf(c11 - c10, wy, c10);
        outc[offc + p] = fmaf(d1 - d0, wz, d0);
        e += GROUPS; rA = tA; rB = tB;
    }
}

// ---- probe A: full loop, stores to masked ws window (x3) ----
__global__ __launch_bounds__(THREADS, 8) void probeA_kernel(
    const float* __restrict__ feat, const int* __restrict__ wsi,
    const float* __restrict__ wsf, float* __restrict__ wsj, unsigned wmask)
{
    PROLOGUE();
    CONVERT_WRITE();
    __syncthreads();
    for (int rep = 0; rep < 3; ++rep) {
        int e = e0;
        float4 rA, rB, rAn, rBn;
        if (e < myEnd) {
            rA = recs2[(size_t)e * 2]; rB = recs2[(size_t)e * 2 + 1];
            if (e + GROUPS < myEnd) {
                rAn = recs2[(size_t)(e + GROUPS) * 2];
                rBn = recs2[(size_t)(e + GROUPS) * 2 + 1];
            }
        }
        while (e < myEnd) {
            float gx = fmaf(rA.y, fx, rA.x);
            float gy = fmaf(rA.w, fy, rA.z);
            int x0 = (int)gx, y0 = (int)gy;
            float wx = __builtin_amdgcn_fractf(gx);
            float wy = __builtin_amdgcn_fractf(gy);
            uint32_t pw = pkrtz(1.0f - wx, wx);
            float wz = rB.x;
            int offc = __float_as_int(rB.y);
            int sl = y0 * SP + x0;
            uint2 q0 = pk2[sl], q1 = pk2[sl + SP];
            float4 tA = rAn, tB = rBn;
            int e2 = e + 2 * GROUPS;
            if (e2 < myEnd) {
                rAn = recs2[(size_t)e2 * 2];
                rBn = recs2[(size_t)e2 * 2 + 1];
            }
            float c00 = xlerp(q0.x, pw);
            float c10 = xlerp(q0.y, pw);
            float c01 = xlerp(q1.x, pw);
            float c11 = xlerp(q1.y, pw);
            float d0 = fmaf(c01 - c00, wy, c00);
            float d1 = fmaf(c11 - c10, wy, c10);
            wsj[((unsigned)(offc + p) ^ ((unsigned)bid << 6)) & wmask] =
                fmaf(d1 - d0, wz, d0);
            e += GROUPS; rA = tA; rB = tB;
        }
    }
}

// ---- probe B: no LDS reads (register junk corners), stores to ws (x3) ----
__global__ __launch_bounds__(THREADS, 8) void probeB_kernel(
    const float* __restrict__ feat, const int* __restrict__ wsi,
    const float* __restrict__ wsf, float* __restrict__ wsj, unsigned wmask)
{
    PROLOGUE();
    CONVERT_WRITE();
    __syncthreads();
    for (int rep = 0; rep < 3; ++rep) {
        int e = e0;
        float4 rA, rB, rAn, rBn;
        if (e < myEnd) {
            rA = recs2[(size_t)e * 2]; rB = recs2[(size_t)e * 2 + 1];
            if (e + GROUPS < myEnd) {
                rAn = recs2[(size_t)(e + GROUPS) * 2];
                rBn = recs2[(size_t)(e + GROUPS) * 2 + 1];
            }
        }
        while (e < myEnd) {
            float gx = fmaf(rA.y, fx, rA.x);
            float gy = fmaf(rA.w, fy, rA.z);
            int x0 = (int)gx, y0 = (int)gy;
            float wx = __builtin_amdgcn_fractf(gx);
            float wy = __builtin_amdgcn_fractf(gy);
            uint32_t pw = pkrtz(1.0f - wx, wx);
            float wz = rB.x;
            int offc = __float_as_int(rB.y);
            int sl = y0 * SP + x0;
            uint2 q0 = make_uint2(pw ^ (unsigned)sl, pw + (unsigned)sl);
            uint2 q1 = make_uint2(pw * 3u + (unsigned)sl, pw - (unsigned)sl);
            float4 tA = rAn, tB = rBn;
            int e2 = e + 2 * GROUPS;
            if (e2 < myEnd) {
                rAn = recs2[(size_t)e2 * 2];
                rBn = recs2[(size_t)e2 * 2 + 1];
            }
            float c00 = xlerp(q0.x, pw);
            float c10 = xlerp(q0.y, pw);
            float c01 = xlerp(q1.x, pw);
            float c11 = xlerp(q1.y, pw);
            float d0 = fmaf(c01 - c00, wy, c00);
            float d1 = fmaf(c11 - c10, wy, c10);
            wsj[((unsigned)(offc + p) ^ ((unsigned)bid << 6)) & wmask] =
                fmaf(d1 - d0, wz, d0);
            e += GROUPS; rA = tA; rB = tB;
        }
    }
}

// ---- probe D: LDS reads issued but asm-sunk; compute on junk (x3) ----
__global__ __launch_bounds__(THREADS, 8) void probeD_kernel(
    const float* __restrict__ feat, const int* __restrict__ wsi,
    const float* __restrict__ wsf, float* __restrict__ wsj, unsigned wmask)
{
    PROLOGUE();
    CONVERT_WRITE();
    __syncthreads();
    for (int rep = 0; rep < 3; ++rep) {
        int e = e0;
        float4 rA, rB, rAn, rBn;
        if (e < myEnd) {
            rA = recs2[(size_t)e * 2]; rB = recs2[(size_t)e * 2 + 1];
            if (e + GROUPS < myEnd) {
                rAn = recs2[(size_t)(e + GROUPS) * 2];
                rBn = recs2[(size_t)(e + GROUPS) * 2 + 1];
            }
        }
        while (e < myEnd) {
            float gx = fmaf(rA.y, fx, rA.x);
            float gy = fmaf(rA.w, fy, rA.z);
            int x0 = (int)gx, y0 = (int)gy;
            float wx = __builtin_amdgcn_fractf(gx);
            float wy = __builtin_amdgcn_fractf(gy);
            uint32_t pw = pkrtz(1.0f - wx, wx);
            float wz = rB.x;
            int offc = __float_as_int(rB.y);
            int sl = y0 * SP + x0;
            uint2 q0 = pk2[sl], q1 = pk2[sl + SP];   // issued, sunk below
            uint2 j0 = make_uint2(pw ^ (unsigned)sl, pw + (unsigned)sl);
            uint2 j1 = make_uint2(pw * 3u + (unsigned)sl, pw - (unsigned)sl);
            float4 tA = rAn, tB = rBn;
            int e2 = e + 2 * GROUPS;
            if (e2 < myEnd) {
                rAn = recs2[(size_t)e2 * 2];
                rBn = recs2[(size_t)e2 * 2 + 1];
            }
            float c00 = xlerp(j0.x, pw);
            float c10 = xlerp(j0.y, pw);
            float c01 = xlerp(j1.x, pw);
            float c11 = xlerp(j1.y, pw);
            float d0 = fmaf(c01 - c00, wy, c00);
            float d1 = fmaf(c11 - c10, wy, c10);
            wsj[((unsigned)(offc + p) ^ ((unsigned)bid << 6)) & wmask] =
                fmaf(d1 - d0, wz, d0);
            asm volatile("" :: "v"(q0.x), "v"(q0.y), "v"(q1.x), "v"(q1.y));
            e += GROUPS; rA = tA; rB = tB;
        }
    }
}

// ---- probe C: staging+convert+barrier only (x8) ----
__global__ __launch_bounds__(THREADS, 8) void probeC_kernel(
    const float* __restrict__ feat, const int* __restrict__ wsi,
    const float* __restrict__ wsf, float* __restrict__ wsj, unsigned wmask)
{
    __shared__ __align__(16) uint2 pk2[64 * SP];
    int bid = blockIdx.x;
    int s   = bid & 511;
    int z0  = bid >> 9;
    int b   = s >> 8;
    int tid = threadIdx.x;
    int base = wsi[b * 64 + z0];
    int end  = wsi[b * 64 + z0 + 1];
    if (base == end) return;
    const float* vol = feat + ((size_t)s << 18) + ((size_t)z0 << 12);
    int y  = tid >> 3;
    int x8 = (tid & 7) << 3;
    float acc = 0.0f;
    for (int rep = 0; rep < 8; ++rep) {
        const float* src = vol + y * 64 + x8 + rep * 4;   // rep-shifted: no CSE
        float4 p0a = *(const float4*)(src);
        float4 p0b = *(const float4*)(src + 4);
        float4 p1a = *(const float4*)(src + 4096);
        float4 p1b = *(const float4*)(src + 4100);
        CONVERT_WRITE();
        __syncthreads();
        acc += p0a.x + p1b.w;
    }
    if (tid == 0) wsj[(unsigned)bid & wmask] = acc;
}

// ---- fallback (ws too small): round-1 kernel, known correct ----
__global__ __launch_bounds__(128) void roialign3d_fallback(
    const float* __restrict__ feat, const float* __restrict__ props,
    float* __restrict__ out)
{
    int bid = blockIdx.x;
    int xcd = bid & 7;
    int j   = bid >> 3;
    int s   = xcd + ((j >> 9) << 3);
    int n   = j & 511;
    int b   = s >> 8;
    int c   = s & 255;
    const float* prop = props + ((size_t)(b * N_ + n)) * 6;
    float x1p = prop[0], y1p = prop[1], z1p = prop[2];
    float x2p = prop[3], y2p = prop[4], z2p = prop[5];
    float sx = (x2p - x1p) * (1.0f / 6.0f);
    float sy = (y2p - y1p) * (1.0f / 6.0f);
    float sz = (z2p - z1p) * (1.0f / 6.0f);
    const float* vol = feat + (size_t)s * (64 * 64 * 64);
    float* o = out + ((size_t)(b * N_ + n) * C_ + c) * 343;
    for (int p = threadIdx.x; p < 343; p += 128) {
        int iz = p / 49, r = p - iz * 49, iy = r / 7, ix = r - iy * 7;
        float gx = x1p + sx * ix, gy = y1p + sy * iy, gz = z1p + sz * iz;
        int x0 = (int)gx, y0 = (int)gy, z0 = (int)gz;
        float wx = gx - x0, wy = gy - y0, wz = gz - z0;
        int x1 = min(x0 + 1, 63), y1 = min(y0 + 1, 63), z1 = min(z0 + 1, 63);
        const float* p00 = vol + ((z0 * 64 + y0) << 6);
        const float* p01 = vol + ((z0 * 64 + y1) << 6);
        const float* p10 = vol + ((z1 * 64 + y0) << 6);
        const float* p11 = vol + ((z1 * 64 + y1) << 6);
        float c00 = p00[x0] + (p00[x1] - p00[x0]) * wx;
        float c01 = p01[x0] + (p01[x1] - p01[x0]) * wx;
        float c10 = p10[x0] + (p10[x1] - p10[x0]) * wx;
        float c11 = p11[x0] + (p11[x1] - p11[x0]) * wx;
        float d0 = c00 + (c01 - c00) * wy;
        float d1 = c10 + (c11 - c10) * wy;
        o[p] = d0 + (d1 - d0) * wz;
    }
}

extern "C" void kernel_launch(void* const* d_in, const int* in_sizes, int n_in,
                              void* d_out, int out_size, void* d_ws, size_t ws_size,
                              hipStream_t stream) {
    const float* feat  = (const float*)d_in[0];
    const float* props = (const float*)d_in[1];
    float* out = (float*)d_out;

    if (ws_size < WS_NEEDED) {
        roialign3d_fallback<<<B_ * C_ * N_, 128, 0, stream>>>(feat, props, out);
        return;
    }
    int*   wsi = (int*)d_ws;
    float* wsf = (float*)d_ws;
    bucket_kernel<<<B_, 256, 0, stream>>>(props, wsi, wsf);
    roialign3d_small_kernel<<<63 * 512, THREADS, 0, stream>>>(feat, wsi, wsf, out);

    // probes: only if ws has a junk window (>= 256 KB of floats beyond records)
    size_t avail_f = (ws_size - WS_NEEDED) / 4;
    if (avail_f >= 65536) {
        unsigned wmask = 1;
        while ((size_t)wmask * 2 <= avail_f) wmask *= 2;
        wmask -= 1;
        float* wsj = (float*)((char*)d_ws + WS_NEEDED);
        probeA_kernel<<<63 * 512, THREADS, 0, stream>>>(feat, wsi, wsf, wsj, wmask);
        probeB_kernel<<<63 * 512, THREADS, 0, stream>>>(feat, wsi, wsf, wsj, wmask);
        probeD_kernel<<<63 * 512, THREADS, 0, stream>>>(feat, wsi, wsf, wsj, wmask);
        probeC_kernel<<<63 * 512, THREADS, 0, stream>>>(feat, wsi, wsf, wsj, wmask);
    }
}

// Round 16
// 306.509 us; speedup vs baseline: 5.2087x; 5.2087x over previous
//
#include <hip/hip_runtime.h>
#include <hip/hip_fp16.h>

// RoIAlign3D: features (B=2, C=256, 64,64,64) f32, proposals (B=2, N=512, 6) f32
// out: (B*N, C, 7, 7, 7) f32
//
// R15 probes: loop ~126us (VALU-bound, 70% busy), stage ~165us, ~zero overlap.
// This round: per-slice ring with DRAIN-FREE barriers.
//   block = slice (512 blocks, 1024 thr, 16 waves, 2 blocks/CU, 67.8 KB LDS).
//   Walk z=0..62; ping-pong two z-pair f16 slot-planes. Per step:
//     1. issue global load plane z+4 (1 float4/thread, sched_barrier pins it)
//     2. entry loop bucket z (reads slot[z&1])          <- load flies under this
//     3. convert planes (z+1 [reg], z+2 [reg]) -> slot[(z+1)&1]
//        (compiler waits vmcnt for z+2 only; z+3/z+4 stay in flight)
//     4. asm lgkmcnt(0) + RAW s_barrier (no vmcnt drain, unlike __syncthreads)
//     5. rotate plane regs
//   Each plane loaded exactly once: 524 MB total staged (was 1.03 GB).
//   Write-after-read safety: slot[(z+1)&1] last read in loop z-1, fenced by
//   step z-1's barrier -> ONE barrier per step suffices.
// Coords in [0,63): floor<=62, +1<=63 -> no clamping; slot x=63 never read.

#define B_      2
#define C_      256
#define N_      512
#define NENT    (N_ * 7)
#define SP      66                  // slots per row (64 used + 2 pad)
#define PLANE_P (64 * SP)           // 4224 uint2 slots per slot-plane
#define THREADS 1024
#define GROUPS  20                  // 20*49 = 980 active lanes
#define REC_F_BASE 128
#define WS_NEEDED ((size_t)REC_F_BASE * 4 + (size_t)B_ * NENT * 8 * 4)

typedef _Float16 h2v __attribute__((ext_vector_type(2)));

__device__ __forceinline__ float gcoord(float lo, float hi, int i) {
    return lo + (hi - lo) * (1.0f / 6.0f) * (float)i;
}
__device__ __forceinline__ uint32_t pkrtz(float a, float b) {
    auto h = __builtin_amdgcn_cvt_pkrtz(a, b);
    return __builtin_bit_cast(uint32_t, h);
}
__device__ __forceinline__ float xlerp(uint32_t pkv, uint32_t pkw) {
#if __has_builtin(__builtin_amdgcn_fdot2)
    return __builtin_amdgcn_fdot2(__builtin_bit_cast(h2v, pkv),
                                  __builtin_bit_cast(h2v, pkw), 0.0f, false);
#else
    h2v v = __builtin_bit_cast(h2v, pkv);
    h2v w = __builtin_bit_cast(h2v, pkw);
    return (float)v[0] * (float)w[0] + (float)v[1] * (float)w[1];
#endif
}

// ---- kernel 1: bucket + per-entry record ----
__global__ __launch_bounds__(256) void bucket_kernel(
    const float* __restrict__ props, int* __restrict__ wsi, float* __restrict__ wsf)
{
    int b = blockIdx.x;
    __shared__ int counts[63];
    __shared__ int starts[64];
    __shared__ int cursors[63];
    int tid = threadIdx.x;
    if (tid < 63) counts[tid] = 0;
    __syncthreads();
    for (int e = tid; e < NENT; e += 256) {
        int n = e / 7, iz = e - n * 7;
        const float* pr = props + (size_t)(b * N_ + n) * 6;
        float gz = gcoord(pr[2], pr[5], iz);
        int z0 = min(max((int)gz, 0), 62);
        atomicAdd(&counts[z0], 1);
    }
    __syncthreads();
    if (tid == 0) {
        int s = 0;
        for (int k = 0; k < 63; ++k) { starts[k] = s; s += counts[k]; }
        starts[63] = s;
    }
    __syncthreads();
    if (tid < 63) cursors[tid] = starts[tid];
    __syncthreads();
    for (int e = tid; e < NENT; e += 256) {
        int n = e / 7, iz = e - n * 7;
        const float* pr = props + (size_t)(b * N_ + n) * 6;
        float x1p = pr[0], y1p = pr[1], z1p = pr[2];
        float x2p = pr[3], y2p = pr[4], z2p = pr[5];
        float gz = gcoord(z1p, z2p, iz);
        int z0 = min(max((int)gz, 0), 62);
        float wz = gz - (float)z0;
        int pos = atomicAdd(&cursors[z0], 1);
        int off = (b * N_ + n) * (C_ * 343) + iz * 49;
        float* r = wsf + REC_F_BASE + (size_t)(b * NENT + pos) * 8;
        r[0] = x1p; r[1] = (x2p - x1p) * (1.0f / 6.0f);
        r[2] = y1p; r[3] = (y2p - y1p) * (1.0f / 6.0f);
        r[4] = wz;  r[5] = __int_as_float(off);
        r[6] = 0.0f; r[7] = 0.0f;
    }
    if (tid < 64) wsi[b * 64 + tid] = starts[tid];
}

// convert planes (A=plane z+1, Bv=plane z+2) into slot-plane dst
#define CONVERT(dstbase, A, Bv) do {                                        \
        float n0_ = __shfl_down((A).x, 1);                                  \
        float n1_ = __shfl_down((Bv).x, 1);                                 \
        uint4 w0_, w1_;                                                     \
        w0_.x = pkrtz((A).x, (A).y);  w0_.y = pkrtz((Bv).x, (Bv).y);        \
        w0_.z = pkrtz((A).y, (A).z);  w0_.w = pkrtz((Bv).y, (Bv).z);        \
        w1_.x = pkrtz((A).z, (A).w);  w1_.y = pkrtz((Bv).z, (Bv).w);        \
        w1_.z = pkrtz((A).w, n0_);    w1_.w = pkrtz((Bv).w, n1_);           \
        uint4* d_ = (uint4*)&(dstbase)[cy * SP + cx4];                      \
        d_[0] = w0_; d_[1] = w1_;                                           \
    } while (0)

// ---- kernel 2: per-slice ring, drain-free barriers ----
__global__ __launch_bounds__(THREADS, 8) void roialign3d_ring_kernel(
    const float* __restrict__ feat,
    const int* __restrict__ wsi,
    const float* __restrict__ wsf,
    float* __restrict__ out)
{
    __shared__ __align__(16) uint2 pk2[2 * PLANE_P];   // 67584 B
    __shared__ int starts[64];

    int s = blockIdx.x;            // slice = b*C + c
    int b = s >> 8;
    int c = s & 255;
    int tid = threadIdx.x;
    const float4* pl = (const float4*)(feat + ((size_t)s << 18));  // + z*1024 + tid

    if (tid < 64) starts[tid] = wsi[b * 64 + tid];

    // prologue: planes 0..3
    float4 P0 = pl[tid];
    float4 Pa = pl[1024 + tid];    // plane 1
    float4 Pb = pl[2048 + tid];    // plane 2
    float4 Pc = pl[3072 + tid];    // plane 3
    float4 Pd;

    int cy  = tid >> 4;            // convert row
    int cx4 = (tid & 15) << 2;     // convert slot base (x)
    CONVERT(pk2, P0, Pa);          // slot-plane 0 = planes 0,1

    // lane map for entry loop
    int g = tid / 49;
    int p = tid - g * 49;
    int iy = p / 7;
    float fx = (float)(p - iy * 7);
    float fy = (float)iy;
    bool active = (g < GROUPS);
    const float4* recs2 = (const float4*)(wsf + REC_F_BASE) + (size_t)(b * NENT) * 2;
    float* outc = out + (size_t)c * 343;

    asm volatile("s_waitcnt lgkmcnt(0)" ::: "memory");
    __builtin_amdgcn_s_barrier();
    asm volatile("" ::: "memory");

    #pragma unroll 1
    for (int z = 0; z < 63; ++z) {
        // 1. issue plane z+4 prefetch (stays in flight across the barrier)
        if (z <= 59) Pd = pl[(size_t)(z + 4) * 1024 + tid];
        __builtin_amdgcn_sched_barrier(0);

        // 2. entry loop for bucket z
        {
            int base = starts[z];
            int myEnd = active ? starts[z + 1] : base;
            int e = base + g;
            const uint2* slotz = pk2 + (z & 1) * PLANE_P;
            float4 rA, rB, rAn, rBn;
            if (e < myEnd) {
                rA = recs2[(size_t)e * 2];
                rB = recs2[(size_t)e * 2 + 1];
                if (e + GROUPS < myEnd) {
                    rAn = recs2[(size_t)(e + GROUPS) * 2];
                    rBn = recs2[(size_t)(e + GROUPS) * 2 + 1];
                }
            }
            while (e < myEnd) {
                float gx = fmaf(rA.y, fx, rA.x);
                float gy = fmaf(rA.w, fy, rA.z);
                int x0 = (int)gx, y0 = (int)gy;
                float wx = __builtin_amdgcn_fractf(gx);
                float wy = __builtin_amdgcn_fractf(gy);
                uint32_t pw = pkrtz(1.0f - wx, wx);
                float wz = rB.x;
                int offc = __float_as_int(rB.y);
                int sl = y0 * SP + x0;
                uint2 q0 = slotz[sl];          // row y0   : {z, z+1}
                uint2 q1 = slotz[sl + SP];     // row y0+1 : {z, z+1}
                float4 tA = rAn, tB = rBn;
                int e2 = e + 2 * GROUPS;
                if (e2 < myEnd) {
                    rAn = recs2[(size_t)e2 * 2];
                    rBn = recs2[(size_t)e2 * 2 + 1];
                }
                float c00 = xlerp(q0.x, pw);
                float c10 = xlerp(q0.y, pw);
                float c01 = xlerp(q1.x, pw);
                float c11 = xlerp(q1.y, pw);
                float d0 = fmaf(c01 - c00, wy, c00);
                float d1 = fmaf(c11 - c10, wy, c10);
                outc[offc + p] = fmaf(d1 - d0, wz, d0);
                e += GROUPS; rA = tA; rB = tB;
            }
        }

        // 3. convert next slot-plane (planes z+1, z+2) -- waits only Pb's load
        if (z <= 61)
            CONVERT(pk2 + ((z + 1) & 1) * PLANE_P, Pa, Pb);

        // 4. drain-free barrier: LDS visible, global loads stay in flight
        if (z < 62) {
            asm volatile("s_waitcnt lgkmcnt(0)" ::: "memory");
            __builtin_amdgcn_s_barrier();
            asm volatile("" ::: "memory");
        }

        // 5. rotate plane registers
        Pa = Pb; Pb = Pc; Pc = Pd;
    }
}

// ---- fallback (ws too small): round-1 kernel, known correct ----
__global__ __launch_bounds__(128) void roialign3d_fallback(
    const float* __restrict__ feat, const float* __restrict__ props,
    float* __restrict__ out)
{
    int bid = blockIdx.x;
    int xcd = bid & 7;
    int j   = bid >> 3;
    int s   = xcd + ((j >> 9) << 3);
    int n   = j & 511;
    int b   = s >> 8;
    int c   = s & 255;
    const float* prop = props + ((size_t)(b * N_ + n)) * 6;
    float x1p = prop[0], y1p = prop[1], z1p = prop[2];
    float x2p = prop[3], y2p = prop[4], z2p = prop[5];
    float sx = (x2p - x1p) * (1.0f / 6.0f);
    float sy = (y2p - y1p) * (1.0f / 6.0f);
    float sz = (z2p - z1p) * (1.0f / 6.0f);
    const float* vol = feat + (size_t)s * (64 * 64 * 64);
    float* o = out + ((size_t)(b * N_ + n) * C_ + c) * 343;
    for (int p = threadIdx.x; p < 343; p += 128) {
        int iz = p / 49, r = p - iz * 49, iy = r / 7, ix = r - iy * 7;
        float gx = x1p + sx * ix, gy = y1p + sy * iy, gz = z1p + sz * iz;
        int x0 = (int)gx, y0 = (int)gy, z0 = (int)gz;
        float wx = gx - x0, wy = gy - y0, wz = gz - z0;
        int x1 = min(x0 + 1, 63), y1 = min(y0 + 1, 63), z1 = min(z0 + 1, 63);
        const float* p00 = vol + ((z0 * 64 + y0) << 6);
        const float* p01 = vol + ((z0 * 64 + y1) << 6);
        const float* p10 = vol + ((z1 * 64 + y0) << 6);
        const float* p11 = vol + ((z1 * 64 + y1) << 6);
        float c00 = p00[x0] + (p00[x1] - p00[x0]) * wx;
        float c01 = p01[x0] + (p01[x1] - p01[x0]) * wx;
        float c10 = p10[x0] + (p10[x1] - p10[x0]) * wx;
        float c11 = p11[x0] + (p11[x1] - p11[x0]) * wx;
        float d0 = c00 + (c01 - c00) * wy;
        float d1 = c10 + (c11 - c10) * wy;
        o[p] = d0 + (d1 - d0) * wz;
    }
}

extern "C" void kernel_launch(void* const* d_in, const int* in_sizes, int n_in,
                              void* d_out, int out_size, void* d_ws, size_t ws_size,
                              hipStream_t stream) {
    const float* feat  = (const float*)d_in[0];
    const float* props = (const float*)d_in[1];
    float* out = (float*)d_out;

    if (ws_size < WS_NEEDED) {
        roialign3d_fallback<<<B_ * C_ * N_, 128, 0, stream>>>(feat, props, out);
        return;
    }
    int*   wsi = (int*)d_ws;
    float* wsf = (float*)d_ws;
    bucket_kernel<<<B_, 256, 0, stream>>>(props, wsi, wsf);
    roialign3d_ring_kernel<<<B_ * C_, THREADS, 0, stream>>>(feat, wsi, wsf, out);
}

// Round 17
// 299.611 us; speedup vs baseline: 5.3286x; 1.0230x over previous
//
#include <hip/hip_runtime.h>
#include <hip/hip_fp16.h>

// RoIAlign3D: features (B=2, C=256, 64,64,64) f32, proposals (B=2, N=512, 6) f32
// out: (B*N, C, 7, 7, 7) f32
//
// FINAL (revert to best-measured, R10 = 290.4 us):
// kernel1: bucket 3584 (roi,iz) entries per batch by z0=floor(gz) into CSR +
//   32 B record {x1p,sx,y1p,sy, wz,out_off,-,-}.
// kernel2: block = (z0, slice-PAIR). Stage planes z0,z0+1 of TWO channel
//   slices as z-pair f16 slots: slot64(y,x) = {pk(h[x],h[x+1])@z0,
//   pk(...)@z0+1} (8 B). Per point per channel: ONE ds_read2_b64 -> all 8
//   corners. Geometry computed once per entry for both channels.
//
// Measured structural ceiling (R8-R16, 9 structures, all 290-320 us):
//   loop ~126 us VALU-issue-bound + stage/feed ~165 us, ~zero overlap in
//   every plain-HIP schedule (block phases synchronize; barriers serialize
//   within-block). 290 ~= 126 + 165. Breaking it needs wave-specialized
//   producer/consumer (spin-flags), out of scope here.

#define B_      2
#define C_      256
#define N_      512
#define NENT    (N_ * 7)
#define SP      66                  // slots per row (64 used + 2 pad)
#define PLANE_P (64 * SP)           // 4224 uint2 slots per slice
#define THREADS 1024
#define GROUPS  20                  // 20*49 = 980 active lanes
#define REC_F_BASE 128
#define WS_NEEDED ((size_t)REC_F_BASE * 4 + (size_t)B_ * NENT * 8 * 4)

typedef _Float16 h2v __attribute__((ext_vector_type(2)));

__device__ __forceinline__ float gcoord(float lo, float hi, int i) {
    return lo + (hi - lo) * (1.0f / 6.0f) * (float)i;
}

__device__ __forceinline__ uint32_t pkrtz(float a, float b) {
    auto h = __builtin_amdgcn_cvt_pkrtz(a, b);
    return __builtin_bit_cast(uint32_t, h);
}

// (1-wx)*v.lo + wx*v.hi with f32 accumulation
__device__ __forceinline__ float xlerp(uint32_t pkv, uint32_t pkw) {
#if __has_builtin(__builtin_amdgcn_fdot2)
    return __builtin_amdgcn_fdot2(__builtin_bit_cast(h2v, pkv),
                                  __builtin_bit_cast(h2v, pkw), 0.0f, false);
#else
    h2v v = __builtin_bit_cast(h2v, pkv);
    h2v w = __builtin_bit_cast(h2v, pkw);
    return (float)v[0] * (float)w[0] + (float)v[1] * (float)w[1];
#endif
}

// ---- kernel 1: bucket + per-entry record ----
__global__ __launch_bounds__(256) void bucket_kernel(
    const float* __restrict__ props, int* __restrict__ wsi, float* __restrict__ wsf)
{
    int b = blockIdx.x;
    __shared__ int counts[63];
    __shared__ int starts[64];
    __shared__ int cursors[63];
    int tid = threadIdx.x;
    if (tid < 63) counts[tid] = 0;
    __syncthreads();
    for (int e = tid; e < NENT; e += 256) {
        int n = e / 7, iz = e - n * 7;
        const float* pr = props + (size_t)(b * N_ + n) * 6;
        float gz = gcoord(pr[2], pr[5], iz);
        int z0 = min(max((int)gz, 0), 62);
        atomicAdd(&counts[z0], 1);
    }
    __syncthreads();
    if (tid == 0) {
        int s = 0;
        for (int k = 0; k < 63; ++k) { starts[k] = s; s += counts[k]; }
        starts[63] = s;
    }
    __syncthreads();
    if (tid < 63) cursors[tid] = starts[tid];
    __syncthreads();
    for (int e = tid; e < NENT; e += 256) {
        int n = e / 7, iz = e - n * 7;
        const float* pr = props + (size_t)(b * N_ + n) * 6;
        float x1p = pr[0], y1p = pr[1], z1p = pr[2];
        float x2p = pr[3], y2p = pr[4], z2p = pr[5];
        float gz = gcoord(z1p, z2p, iz);
        int z0 = min(max((int)gz, 0), 62);
        float wz = gz - (float)z0;
        int pos = atomicAdd(&cursors[z0], 1);
        int off = (b * N_ + n) * (C_ * 343) + iz * 49;
        float* r = wsf + REC_F_BASE + (size_t)(b * NENT + pos) * 8;
        r[0] = x1p; r[1] = (x2p - x1p) * (1.0f / 6.0f);
        r[2] = y1p; r[3] = (y2p - y1p) * (1.0f / 6.0f);
        r[4] = wz;  r[5] = __int_as_float(off);
        r[6] = 0.0f; r[7] = 0.0f;
    }
    if (tid < 64) wsi[b * 64 + tid] = starts[tid];
}

// ---- kernel 2: block = (z0, slice-pair); z-pair slots, 2 channels/entry ----
__global__ __launch_bounds__(THREADS, 8) void roialign3d_zpair_kernel(
    const float* __restrict__ feat,
    const int* __restrict__ wsi,
    const float* __restrict__ wsf,
    float* __restrict__ out)
{
    __shared__ __align__(16) uint2 pk2[2 * PLANE_P];   // 67584 B

    int bid = blockIdx.x;
    int pi  = bid & 255;           // slice-pair -> XCD pi%8 every round
    int z0  = bid >> 8;            // 0..62
    int b   = pi >> 7;
    int c0  = (pi & 127) << 1;     // channels c0, c0+1
    int tid = threadIdx.x;

    int base = wsi[b * 64 + z0];
    int end  = wsi[b * 64 + z0 + 1];
    if (base == end) return;       // empty bucket: skip staging entirely

    const float* vol0 = feat + ((size_t)((b << 8) + c0) << 18) + ((size_t)z0 << 12);
    const float* vol1 = vol0 + (1 << 18);

    // ---- stage loads: 2 slices x planes z0,z0+1 (64 KB in flight) ----
    float4 a0 = *(const float4*)(vol0 + (tid << 2));
    float4 a1 = *(const float4*)(vol0 + 4096 + (tid << 2));
    float4 b0 = *(const float4*)(vol1 + (tid << 2));
    float4 b1 = *(const float4*)(vol1 + 4096 + (tid << 2));

    // dense lane map + record prefetch (behind plane loads)
    int g = tid / 49;
    int p = tid - g * 49;
    int iy = p / 7;
    float fx = (float)(p - iy * 7);
    float fy = (float)iy;
    const float4* recs = (const float4*)(wsf + REC_F_BASE);
    const int rbase = b * NENT;
    int myEnd = (g < GROUPS) ? end : base;
    int e = base + g;
    float4 rA, rB, rAn, rBn;
    if (e < myEnd) {
        rA = recs[(size_t)(rbase + e) * 2];
        rB = recs[(size_t)(rbase + e) * 2 + 1];
        if (e + GROUPS < myEnd) {
            rAn = recs[(size_t)(rbase + e + GROUPS) * 2];
            rBn = recs[(size_t)(rbase + e + GROUPS) * 2 + 1];
        }
    }

    // ---- convert + write: slot64(y,x) = {xpair@z0, xpair@z0+1} ----
    {
        int swb = (tid >> 4) * SP + ((tid & 15) << 2);   // uint2 slot index
        float a0n = __shfl_down(a0.x, 1);
        float a1n = __shfl_down(a1.x, 1);
        float b0n = __shfl_down(b0.x, 1);
        float b1n = __shfl_down(b1.x, 1);
        uint2* d0 = &pk2[swb];
        uint2* d1 = &pk2[PLANE_P + swb];
        d0[0] = make_uint2(pkrtz(a0.x, a0.y), pkrtz(a1.x, a1.y));
        d0[1] = make_uint2(pkrtz(a0.y, a0.z), pkrtz(a1.y, a1.z));
        d0[2] = make_uint2(pkrtz(a0.z, a0.w), pkrtz(a1.z, a1.w));
        d0[3] = make_uint2(pkrtz(a0.w, a0n),  pkrtz(a1.w, a1n));
        d1[0] = make_uint2(pkrtz(b0.x, b0.y), pkrtz(b1.x, b1.y));
        d1[1] = make_uint2(pkrtz(b0.y, b0.z), pkrtz(b1.y, b1.z));
        d1[2] = make_uint2(pkrtz(b0.z, b0.w), pkrtz(b1.z, b1.w));
        d1[3] = make_uint2(pkrtz(b0.w, b0n),  pkrtz(b1.w, b1n));
    }
    __syncthreads();

    // ---- entry loop: geometry once, two channels per entry ----
    float* outc = out + (size_t)c0 * 343;
    while (e < myEnd) {
        float gx = fmaf(rA.y, fx, rA.x);
        float gy = fmaf(rA.w, fy, rA.z);
        int x0 = (int)gx, y0 = (int)gy;
        float wx = __builtin_amdgcn_fractf(gx);
        float wy = __builtin_amdgcn_fractf(gy);
        uint32_t pw = pkrtz(1.0f - wx, wx);
        float wz = rB.x;
        int offc = __float_as_int(rB.y);
        int sl = y0 * SP + x0;
        uint2 qa0 = pk2[sl],           qa1 = pk2[sl + SP];           // slice 0
        uint2 qb0 = pk2[PLANE_P + sl], qb1 = pk2[PLANE_P + sl + SP]; // slice 1

        // rotate record pipeline; prefetch e+2*GROUPS
        float4 tA = rAn, tB = rBn;
        int e2 = e + 2 * GROUPS;
        if (e2 < myEnd) {
            rAn = recs[(size_t)(rbase + e2) * 2];
            rBn = recs[(size_t)(rbase + e2) * 2 + 1];
        }

        // channel c0
        {
            float c00 = xlerp(qa0.x, pw);   // z0  , y0
            float c10 = xlerp(qa0.y, pw);   // z0+1, y0
            float c01 = xlerp(qa1.x, pw);   // z0  , y0+1
            float c11 = xlerp(qa1.y, pw);   // z0+1, y0+1
            float d0 = fmaf(c01 - c00, wy, c00);
            float d1 = fmaf(c11 - c10, wy, c10);
            outc[offc + p] = fmaf(d1 - d0, wz, d0);
        }
        // channel c0+1
        {
            float c00 = xlerp(qb0.x, pw);
            float c10 = xlerp(qb0.y, pw);
            float c01 = xlerp(qb1.x, pw);
            float c11 = xlerp(qb1.y, pw);
            float d0 = fmaf(c01 - c00, wy, c00);
            float d1 = fmaf(c11 - c10, wy, c10);
            outc[offc + 343 + p] = fmaf(d1 - d0, wz, d0);
        }

        e += GROUPS; rA = tA; rB = tB;
    }
}

// ---- fallback (ws too small): round-1 kernel, known correct ----
__global__ __launch_bounds__(128) void roialign3d_fallback(
    const float* __restrict__ feat, const float* __restrict__ props,
    float* __restrict__ out)
{
    int bid = blockIdx.x;
    int xcd = bid & 7;
    int j   = bid >> 3;
    int s   = xcd + ((j >> 9) << 3);
    int n   = j & 511;
    int b   = s >> 8;
    int c   = s & 255;
    const float* prop = props + ((size_t)(b * N_ + n)) * 6;
    float x1p = prop[0], y1p = prop[1], z1p = prop[2];
    float x2p = prop[3], y2p = prop[4], z2p = prop[5];
    float sx = (x2p - x1p) * (1.0f / 6.0f);
    float sy = (y2p - y1p) * (1.0f / 6.0f);
    float sz = (z2p - z1p) * (1.0f / 6.0f);
    const float* vol = feat + (size_t)s * (64 * 64 * 64);
    float* o = out + ((size_t)(b * N_ + n) * C_ + c) * 343;
    for (int p = threadIdx.x; p < 343; p += 128) {
        int iz = p / 49, r = p - iz * 49, iy = r / 7, ix = r - iy * 7;
        float gx = x1p + sx * ix, gy = y1p + sy * iy, gz = z1p + sz * iz;
        int x0 = (int)gx, y0 = (int)gy, z0 = (int)gz;
        float wx = gx - x0, wy = gy - y0, wz = gz - z0;
        int x1 = min(x0 + 1, 63), y1 = min(y0 + 1, 63), z1 = min(z0 + 1, 63);
        const float* p00 = vol + ((z0 * 64 + y0) << 6);
        const float* p01 = vol + ((z0 * 64 + y1) << 6);
        const float* p10 = vol + ((z1 * 64 + y0) << 6);
        const float* p11 = vol + ((z1 * 64 + y1) << 6);
        float c00 = p00[x0] + (p00[x1] - p00[x0]) * wx;
        float c01 = p01[x0] + (p01[x1] - p01[x0]) * wx;
        float c10 = p10[x0] + (p10[x1] - p10[x0]) * wx;
        float c11 = p11[x0] + (p11[x1] - p11[x0]) * wx;
        float d0 = c00 + (c01 - c00) * wy;
        float d1 = c10 + (c11 - c10) * wy;
        o[p] = d0 + (d1 - d0) * wz;
    }
}

extern "C" void kernel_launch(void* const* d_in, const int* in_sizes, int n_in,
                              void* d_out, int out_size, void* d_ws, size_t ws_size,
                              hipStream_t stream) {
    const float* feat  = (const float*)d_in[0];
    const float* props = (const float*)d_in[1];
    float* out = (float*)d_out;

    if (ws_size < WS_NEEDED) {
        roialign3d_fallback<<<B_ * C_ * N_, 128, 0, stream>>>(feat, props, out);
        return;
    }
    int*   wsi = (int*)d_ws;
    float* wsf = (float*)d_ws;
    bucket_kernel<<<B_, 256, 0, stream>>>(props, wsi, wsf);
    roialign3d_zpair_kernel<<<63 * 256, THREADS, 0, stream>>>(feat, wsi, wsf, out);
}